// Round 1
// baseline (474.684 us; speedup 1.0000x reference)
//
#include <hip/hip_runtime.h>
#include <math.h>

#define NN 8192
#define KK 2048   // 2*D
#define HH 100
#define BM 32
#define BK 16
#define CAP 1024

// Fused encoder: s[i] = b2 + sum_h relu(b1[h] + [q_i;x_i] . W1[:,h]) * W2[h]
__global__ __launch_bounds__(256) void encoder_kernel(
    const float* __restrict__ q, const float* __restrict__ x,
    const float* __restrict__ W1, const float* __restrict__ b1,
    const float* __restrict__ W2, const float* __restrict__ b2,
    float* __restrict__ s_out)
{
    __shared__ float As[BK][BM + 4];   // [k][row], padded
    __shared__ float Ws[BK][HH + 4];   // [k][h], padded
    const int t = threadIdx.x;
    const int row0 = blockIdx.x * BM;

    const int tc = t & 31;   // column lane 0..31
    const int tr = t >> 5;   // 0..7
    const int r0 = tr * 4;   // 4 rows per thread

    float acc[4][4];
#pragma unroll
    for (int i = 0; i < 4; i++)
#pragma unroll
        for (int j = 0; j < 4; j++) acc[i][j] = 0.f;

    const int srow = t >> 3;        // 0..31
    const int skk  = (t & 7) * 2;   // 0,2,..,14

    for (int kc = 0; kc < KK; kc += BK) {
        // stage A tile (rows row0..row0+31, k = kc..kc+15), f32
        {
            const float* src = (kc < 1024)
                ? (q + (size_t)(row0 + srow) * 1024 + (kc + skk))
                : (x + (size_t)(row0 + srow) * 1024 + (kc - 1024 + skk));
            float2 v = *(const float2*)src;
            As[skk][srow]     = v.x;
            As[skk + 1][srow] = v.y;
        }
        // stage W1 tile (k rows kc..kc+15, all 100 cols)
        for (int idx = t; idx < BK * HH; idx += 256) {
            int kk = idx / HH;
            int h  = idx - kk * HH;
            Ws[kk][h] = W1[(size_t)(kc + kk) * HH + h];
        }
        __syncthreads();
#pragma unroll
        for (int k = 0; k < BK; ++k) {
            float4 a = *(const float4*)&As[k][r0];
            float av[4] = {a.x, a.y, a.z, a.w};
#pragma unroll
            for (int c = 0; c < 4; ++c) {
                int col = tc + 32 * c;
                if (col < HH) {
                    float bv = Ws[k][col];
#pragma unroll
                    for (int i = 0; i < 4; i++) acc[i][c] = fmaf(av[i], bv, acc[i][c]);
                }
            }
        }
        __syncthreads();
    }

    // epilogue: relu + W2 dot, reduce across the 32 column lanes
    const float b2v = b2[0];
    float bb[4], ww[4];
#pragma unroll
    for (int c = 0; c < 4; ++c) {
        int col = tc + 32 * c;
        bb[c] = (col < HH) ? b1[col] : 0.f;
        ww[c] = (col < HH) ? W2[col] : 0.f;
    }
#pragma unroll
    for (int i = 0; i < 4; ++i) {
        float v = 0.f;
#pragma unroll
        for (int c = 0; c < 4; ++c) {
            int col = tc + 32 * c;
            if (col < HH) {
                float hv = acc[i][c] + bb[c];
                hv = fmaxf(hv, 0.f);
                v = fmaf(hv, ww[c], v);
            }
        }
#pragma unroll
        for (int off = 16; off > 0; off >>= 1) v += __shfl_xor(v, off, 32);
        if (tc == 0) s_out[row0 + r0 + i] = v + b2v;
    }
}

// Per-batch pairwise softplus(s_neg - s_pos) sum.
__global__ __launch_bounds__(256) void pair_kernel(
    const int* __restrict__ b, const int* __restrict__ y,
    const float* __restrict__ s, float* __restrict__ partial,
    float* __restrict__ pcount)
{
    __shared__ float sp[CAP];
    __shared__ float sn[CAP];
    __shared__ int c1, c0;
    __shared__ float wsum[4];
    const int g = blockIdx.x;
    const int t = threadIdx.x;
    if (t == 0) { c1 = 0; c0 = 0; }
    __syncthreads();
    for (int i = t; i < NN; i += 256) {
        if (b[i] == g) {
            float sv = s[i];
            if (y[i]) { int idx = atomicAdd(&c1, 1); if (idx < CAP) sp[idx] = sv; }
            else      { int idx = atomicAdd(&c0, 1); if (idx < CAP) sn[idx] = sv; }
        }
    }
    __syncthreads();
    const int n1 = min(c1, CAP);
    const int n0 = min(c0, CAP);
    float acc = 0.f;
    for (int p = t; p < n1; p += 256) {
        float v = sp[p];
        for (int j = 0; j < n0; ++j) {
            float u = sn[j] - v;                    // s_neg - s_pos
            acc += fmaxf(u, 0.f) + log1pf(expf(-fabsf(u)));
        }
    }
#pragma unroll
    for (int off = 32; off > 0; off >>= 1) acc += __shfl_xor(acc, off, 64);
    const int wid = t >> 6, lane = t & 63;
    if (lane == 0) wsum[wid] = acc;
    __syncthreads();
    if (t == 0) {
        partial[g] = wsum[0] + wsum[1] + wsum[2] + wsum[3];
        pcount[g]  = (float)n1 * (float)n0;
    }
}

__global__ void finalize_kernel(const float* __restrict__ partial,
                                const float* __restrict__ pcount,
                                float* __restrict__ out)
{
    int t = threadIdx.x;  // 64 threads
    float sv = (t < 32) ? partial[t] : 0.f;
    float cv = (t < 32) ? pcount[t] : 0.f;
#pragma unroll
    for (int off = 32; off > 0; off >>= 1) {
        sv += __shfl_xor(sv, off, 64);
        cv += __shfl_xor(cv, off, 64);
    }
    if (t == 0) out[0] = sv / cv;
}

extern "C" void kernel_launch(void* const* d_in, const int* in_sizes, int n_in,
                              void* d_out, int out_size, void* d_ws, size_t ws_size,
                              hipStream_t stream)
{
    const int*   b  = (const int*)d_in[0];
    const float* q  = (const float*)d_in[1];
    const float* x  = (const float*)d_in[2];
    const int*   y  = (const int*)d_in[3];
    const float* W1 = (const float*)d_in[4];
    const float* b1 = (const float*)d_in[5];
    const float* W2 = (const float*)d_in[6];
    const float* b2 = (const float*)d_in[7];
    float* out = (float*)d_out;

    float* s       = (float*)d_ws;   // NN floats
    float* partial = s + NN;         // 32 floats
    float* pcount  = partial + 32;   // 32 floats

    encoder_kernel<<<NN / BM, 256, 0, stream>>>(q, x, W1, b1, W2, b2, s);
    pair_kernel<<<32, 256, 0, stream>>>(b, y, s, partial, pcount);
    finalize_kernel<<<1, 64, 0, stream>>>(partial, pcount, out);
}

// Round 2
// 112.810 us; speedup vs baseline: 4.2078x; 4.2078x over previous
//
#include <hip/hip_runtime.h>
#include <math.h>
#include <stdint.h>

#define NN 8192
#define DD 1024
#define KT 2048   // 2*D
#define HH 100
#define HP 128    // padded hidden
#define CAP 1024

typedef short short8 __attribute__((ext_vector_type(8)));
typedef float f32x4 __attribute__((ext_vector_type(4)));

__device__ __forceinline__ short f2bf(float f) {
    uint32_t u = __builtin_bit_cast(uint32_t, f);
    u += 0x7FFF + ((u >> 16) & 1);   // round-to-nearest-even
    return (short)(u >> 16);
}

// W1 fp32 [2048][100] -> w1t bf16-bits [128][2048] (transposed, zero-padded cols)
__global__ __launch_bounds__(256) void prep_w1t(const float* __restrict__ W1,
                                                short* __restrict__ w1t)
{
    const int col = blockIdx.x;          // 0..127
    const int k0  = threadIdx.x * 8;     // 0..2040
    short8 r;
    if (col < HH) {
#pragma unroll
        for (int j = 0; j < 8; ++j) r[j] = f2bf(W1[(size_t)(k0 + j) * HH + col]);
    } else {
#pragma unroll
        for (int j = 0; j < 8; ++j) r[j] = 0;
    }
    *(short8*)(w1t + (size_t)col * KT + k0) = r;
}

// One wave (64 thr) per 16 rows. Register-only bf16 MFMA, no LDS, no barriers.
__global__ __launch_bounds__(64) void encoder_mfma(
    const float* __restrict__ q, const float* __restrict__ x,
    const short* __restrict__ w1t,
    const float* __restrict__ b1, const float* __restrict__ W2,
    const float* __restrict__ b2, float* __restrict__ s_out)
{
    const int l  = threadIdx.x;
    const int lr = l & 15;           // row-in-tile (A) / col-in-tile (B,C)
    const int lg = l >> 4;           // 0..3 k-group
    const int ko = lg * 8;           // k slot offset
    const int r0 = blockIdx.x * 16;
    const float* arow = q + (size_t)(r0 + lr) * DD;
    const float* xrow = x + (size_t)(r0 + lr) * DD;

    f32x4 acc[8];
#pragma unroll
    for (int t = 0; t < 8; ++t) acc[t] = (f32x4)0.f;

    struct ARaw { float4 u, v; };
    auto loadAraw = [&](int kc) -> ARaw {
        const float* p = (kc < DD) ? (arow + kc + ko) : (xrow + (kc - DD) + ko);
        ARaw r;
        r.u = *(const float4*)p;
        r.v = *(const float4*)(p + 4);
        return r;
    };
    auto loadB = [&](int kc, short8 B[8]) {
        const short* bp = w1t + kc + ko;
#pragma unroll
        for (int t = 0; t < 8; ++t)
            B[t] = *(const short8*)(bp + (size_t)(t * 16 + lr) * KT);
    };
    auto domfma = [&](const ARaw& r, short8 B[8]) {
        short8 a;
        a[0]=f2bf(r.u.x); a[1]=f2bf(r.u.y); a[2]=f2bf(r.u.z); a[3]=f2bf(r.u.w);
        a[4]=f2bf(r.v.x); a[5]=f2bf(r.v.y); a[6]=f2bf(r.v.z); a[7]=f2bf(r.v.w);
#pragma unroll
        for (int t = 0; t < 8; ++t)
            acc[t] = __builtin_amdgcn_mfma_f32_16x16x32_bf16(a, B[t], acc[t], 0, 0, 0);
    };

    ARaw A0, A1;
    short8 B0[8], B1[8];
    A0 = loadAraw(0); loadB(0, B0);
#pragma unroll 1
    for (int i = 0; i < 31; ++i) {
        const int kc = i * 64;
        A1 = loadAraw(kc + 32); loadB(kc + 32, B1);
        domfma(A0, B0);
        A0 = loadAraw(kc + 64); loadB(kc + 64, B0);
        domfma(A1, B1);
    }
    A1 = loadAraw(KT - 32); loadB(KT - 32, B1);
    domfma(A0, B0);
    domfma(A1, B1);

    // epilogue: relu + W2 dot; reduce over the 16 lanes of each k-group
    float bb[8], ww[8];
#pragma unroll
    for (int t = 0; t < 8; ++t) {
        const int col = t * 16 + lr;
        const bool v = col < HH;
        bb[t] = v ? b1[col] : 0.f;
        ww[t] = v ? W2[col] : 0.f;
    }
    const float b2v = b2[0];
#pragma unroll
    for (int r = 0; r < 4; ++r) {
        float sum = 0.f;
#pragma unroll
        for (int t = 0; t < 8; ++t) {
            float h = acc[t][r] + bb[t];
            sum = fmaf(fmaxf(h, 0.f), ww[t], sum);
        }
        sum += __shfl_xor(sum, 1);
        sum += __shfl_xor(sum, 2);
        sum += __shfl_xor(sum, 4);
        sum += __shfl_xor(sum, 8);
        if (lr == 0) s_out[r0 + lg * 4 + r] = sum + b2v;
    }
}

// Per-batch pairwise softplus(s_neg - s_pos) sum.
__global__ __launch_bounds__(256) void pair_kernel(
    const int* __restrict__ b, const int* __restrict__ y,
    const float* __restrict__ s, float* __restrict__ partial,
    float* __restrict__ pcount)
{
    __shared__ float sp[CAP];
    __shared__ float sn[CAP];
    __shared__ int c1, c0;
    __shared__ float wsum[4];
    const int g = blockIdx.x;
    const int t = threadIdx.x;
    if (t == 0) { c1 = 0; c0 = 0; }
    __syncthreads();
    for (int i = t; i < NN; i += 256) {
        if (b[i] == g) {
            float sv = s[i];
            if (y[i]) { int idx = atomicAdd(&c1, 1); if (idx < CAP) sp[idx] = sv; }
            else      { int idx = atomicAdd(&c0, 1); if (idx < CAP) sn[idx] = sv; }
        }
    }
    __syncthreads();
    const int n1 = min(c1, CAP);
    const int n0 = min(c0, CAP);
    float acc = 0.f;
    for (int p = t; p < n1; p += 256) {
        float v = sp[p];
        for (int j = 0; j < n0; ++j) {
            float u = sn[j] - v;                    // s_neg - s_pos
            acc += fmaxf(u, 0.f) + log1pf(expf(-fabsf(u)));
        }
    }
#pragma unroll
    for (int off = 32; off > 0; off >>= 1) acc += __shfl_xor(acc, off, 64);
    const int wid = t >> 6, lane = t & 63;
    if (lane == 0) wsum[wid] = acc;
    __syncthreads();
    if (t == 0) {
        partial[g] = wsum[0] + wsum[1] + wsum[2] + wsum[3];
        pcount[g]  = (float)n1 * (float)n0;
    }
}

__global__ void finalize_kernel(const float* __restrict__ partial,
                                const float* __restrict__ pcount,
                                float* __restrict__ out)
{
    int t = threadIdx.x;  // 64 threads
    float sv = (t < 32) ? partial[t] : 0.f;
    float cv = (t < 32) ? pcount[t] : 0.f;
#pragma unroll
    for (int off = 32; off > 0; off >>= 1) {
        sv += __shfl_xor(sv, off, 64);
        cv += __shfl_xor(cv, off, 64);
    }
    if (t == 0) out[0] = sv / cv;
}

extern "C" void kernel_launch(void* const* d_in, const int* in_sizes, int n_in,
                              void* d_out, int out_size, void* d_ws, size_t ws_size,
                              hipStream_t stream)
{
    const int*   b  = (const int*)d_in[0];
    const float* q  = (const float*)d_in[1];
    const float* x  = (const float*)d_in[2];
    const int*   y  = (const int*)d_in[3];
    const float* W1 = (const float*)d_in[4];
    const float* b1 = (const float*)d_in[5];
    const float* W2 = (const float*)d_in[6];
    const float* b2 = (const float*)d_in[7];
    float* out = (float*)d_out;

    float* s       = (float*)d_ws;          // NN floats
    float* partial = s + NN;                // 32
    float* pcount  = partial + 32;          // 32
    short* w1t     = (short*)((char*)d_ws + (size_t)(NN + 64) * 4);  // 128*2048 bf16

    prep_w1t<<<HP, 256, 0, stream>>>(W1, w1t);
    encoder_mfma<<<NN / 16, 64, 0, stream>>>(q, x, w1t, b1, W2, b2, s);
    pair_kernel<<<32, 256, 0, stream>>>(b, y, s, partial, pcount);
    finalize_kernel<<<1, 64, 0, stream>>>(partial, pcount, out);
}

// Round 4
// 83.691 us; speedup vs baseline: 5.6719x; 1.3479x over previous
//
#include <hip/hip_runtime.h>
#include <math.h>
#include <stdint.h>

#define NN 8192
#define DD 1024
#define KT 2048   // 2*D
#define HH 100
#define HP 128    // padded hidden
#define LCAP 512  // per-batch per-label list capacity (expected ~128)
#define NB 32     // batches

typedef short short8 __attribute__((ext_vector_type(8)));
typedef float f32x4 __attribute__((ext_vector_type(4)));

__device__ __forceinline__ short f2bf(float f) {
    uint32_t u = __builtin_bit_cast(uint32_t, f);
    u += 0x7FFF + ((u >> 16) & 1);   // round-to-nearest-even
    return (short)(u >> 16);
}

// W1 fp32 [2048][100] -> w1t bf16-bits [128][2048] (transposed, zero-padded cols)
__global__ __launch_bounds__(256) void prep_w1t(const float* __restrict__ W1,
                                                short* __restrict__ w1t)
{
    const int col = blockIdx.x;          // 0..127
    const int k0  = threadIdx.x * 8;     // 0..2040
    short8 r;
    if (col < HH) {
#pragma unroll
        for (int j = 0; j < 8; ++j) r[j] = f2bf(W1[(size_t)(k0 + j) * HH + col]);
    } else {
#pragma unroll
        for (int j = 0; j < 8; ++j) r[j] = 0;
    }
    *(short8*)(w1t + (size_t)col * KT + k0) = r;
}

// 512 threads = 8 waves per block; block owns 16 rows; wave w owns K-slice
// [w*256, w*256+256). LDS-reduce pre-activations, wave-0 epilogue pushes
// scores into per-batch pos/neg lists (global atomics).
__global__ __launch_bounds__(512, 4) void encoder_mfma(
    const float* __restrict__ q, const float* __restrict__ x,
    const short* __restrict__ w1t,
    const float* __restrict__ b1, const float* __restrict__ W2,
    const float* __restrict__ b2,
    const int* __restrict__ bidx, const int* __restrict__ y,
    float* __restrict__ sp, float* __restrict__ sn,
    int* __restrict__ cnt1, int* __restrict__ cnt0)
{
    __shared__ float buf[7][16][HP + 4];
    const int t  = threadIdx.x;
    const int w  = t >> 6;           // wave 0..7
    const int l  = t & 63;
    const int lr = l & 15;           // A row / B col / C col
    const int lg = l >> 4;           // 0..3
    const int ko = lg * 8;           // k slot offset within 32-chunk
    const int r0 = blockIdx.x * 16;
    const int kbase = w << 8;        // 256-deep K slice

    const float* arow = (kbase < DD)
        ? (q + (size_t)(r0 + lr) * DD + kbase + ko)
        : (x + (size_t)(r0 + lr) * DD + (kbase - DD) + ko);
    const short* bbase = w1t + kbase + ko + (size_t)lr * KT;

    f32x4 acc[8];
#pragma unroll
    for (int tt = 0; tt < 8; ++tt) acc[tt] = (f32x4)0.f;

#pragma unroll
    for (int step = 0; step < 8; ++step) {
        const float* p = arow + step * 32;
        float4 u = *(const float4*)p;
        float4 v = *(const float4*)(p + 4);
        short8 a;
        a[0]=f2bf(u.x); a[1]=f2bf(u.y); a[2]=f2bf(u.z); a[3]=f2bf(u.w);
        a[4]=f2bf(v.x); a[5]=f2bf(v.y); a[6]=f2bf(v.z); a[7]=f2bf(v.w);
#pragma unroll
        for (int tt = 0; tt < 8; ++tt) {
            short8 bv = *(const short8*)(bbase + step * 32 + (size_t)(tt * 16) * KT);
            acc[tt] = __builtin_amdgcn_mfma_f32_16x16x32_bf16(a, bv, acc[tt], 0, 0, 0);
        }
    }

    if (w > 0) {
#pragma unroll
        for (int tt = 0; tt < 8; ++tt)
#pragma unroll
            for (int r = 0; r < 4; ++r)
                buf[w - 1][lg * 4 + r][tt * 16 + lr] = acc[tt][r];
    }
    __syncthreads();
    if (w == 0) {
        // fold the other 7 waves' partials
#pragma unroll
        for (int tt = 0; tt < 8; ++tt)
#pragma unroll
            for (int r = 0; r < 4; ++r) {
                float hs = acc[tt][r];
#pragma unroll
                for (int wv = 0; wv < 7; ++wv)
                    hs += buf[wv][lg * 4 + r][tt * 16 + lr];
                acc[tt][r] = hs;
            }
        float bb[8], ww[8];
#pragma unroll
        for (int tt = 0; tt < 8; ++tt) {
            const int col = tt * 16 + lr;
            const bool vld = col < HH;
            bb[tt] = vld ? b1[col] : 0.f;
            ww[tt] = vld ? W2[col] : 0.f;
        }
        const float b2v = b2[0];
#pragma unroll
        for (int r = 0; r < 4; ++r) {
            float sum = 0.f;
#pragma unroll
            for (int tt = 0; tt < 8; ++tt) {
                float h = acc[tt][r] + bb[tt];
                sum = fmaf(fmaxf(h, 0.f), ww[tt], sum);
            }
            sum += __shfl_xor(sum, 1);
            sum += __shfl_xor(sum, 2);
            sum += __shfl_xor(sum, 4);
            sum += __shfl_xor(sum, 8);
            if (lr == 0) {
                const float sv = sum + b2v;
                const int i = r0 + lg * 4 + r;
                const int g = bidx[i];
                if (y[i]) {
                    int idx = atomicAdd(&cnt1[g], 1);
                    if (idx < LCAP) sp[g * LCAP + idx] = sv;
                } else {
                    int idx = atomicAdd(&cnt0[g], 1);
                    if (idx < LCAP) sn[g * LCAP + idx] = sv;
                }
            }
        }
    }
}

// grid = NB*8 blocks; block (g, sl) handles pos indices p ≡ sl (mod 8).
__global__ __launch_bounds__(256) void pairsum_kernel(
    const float* __restrict__ sp, const float* __restrict__ sn,
    const int* __restrict__ cnt1, const int* __restrict__ cnt0,
    float* __restrict__ partial)
{
    __shared__ float lsn[LCAP];
    __shared__ float lsp[64];
    __shared__ float wsum[4];
    const int g  = blockIdx.x >> 3;
    const int sl = blockIdx.x & 7;
    const int t  = threadIdx.x;
    const int n1 = min(cnt1[g], LCAP);
    const int n0 = min(cnt0[g], LCAP);
    for (int j = t; j < n0; j += 256) lsn[j] = sn[g * LCAP + j];
    const int np = (n1 > sl) ? ((n1 - sl + 7) >> 3) : 0;
    for (int j = t; j < np; j += 256) lsp[j] = sp[g * LCAP + sl + j * 8];
    __syncthreads();
    float acc = 0.f;
    const int total = np * n0;
    for (int u = t; u < total; u += 256) {
        const int ip = u / n0;
        const int j  = u - ip * n0;
        const float d  = lsn[j] - lsp[ip];          // s_neg - s_pos
        const float ad = fabsf(d);
        const float z  = __builtin_exp2f(-ad * 1.44269504f);
        acc += fmaxf(d, 0.f) + __builtin_log2f(1.f + z) * 0.69314718f;
    }
#pragma unroll
    for (int off = 32; off > 0; off >>= 1) acc += __shfl_xor(acc, off, 64);
    const int wid = t >> 6, lane = t & 63;
    if (lane == 0) wsum[wid] = acc;
    __syncthreads();
    if (t == 0) partial[blockIdx.x] = wsum[0] + wsum[1] + wsum[2] + wsum[3];
}

__global__ __launch_bounds__(256) void finalize_kernel(
    const float* __restrict__ partial,
    const int* __restrict__ cnt1, const int* __restrict__ cnt0,
    float* __restrict__ out)
{
    __shared__ float ws_[4], wc_[4];
    const int t = threadIdx.x;
    float sv = partial[t];   // 256 entries
    float cv = 0.f;
    if (t < NB) cv = (float)min(cnt1[t], LCAP) * (float)min(cnt0[t], LCAP);
#pragma unroll
    for (int off = 32; off > 0; off >>= 1) {
        sv += __shfl_xor(sv, off, 64);
        cv += __shfl_xor(cv, off, 64);
    }
    const int wid = t >> 6, lane = t & 63;
    if (lane == 0) { ws_[wid] = sv; wc_[wid] = cv; }
    __syncthreads();
    if (t == 0)
        out[0] = (ws_[0] + ws_[1] + ws_[2] + ws_[3]) /
                 (wc_[0] + wc_[1] + wc_[2] + wc_[3]);
}

extern "C" void kernel_launch(void* const* d_in, const int* in_sizes, int n_in,
                              void* d_out, int out_size, void* d_ws, size_t ws_size,
                              hipStream_t stream)
{
    const int*   b  = (const int*)d_in[0];
    const float* q  = (const float*)d_in[1];
    const float* x  = (const float*)d_in[2];
    const int*   y  = (const int*)d_in[3];
    const float* W1 = (const float*)d_in[4];
    const float* b1 = (const float*)d_in[5];
    const float* W2 = (const float*)d_in[6];
    const float* b2 = (const float*)d_in[7];
    float* out = (float*)d_out;

    char* base = (char*)d_ws;
    short* w1t     = (short*)base;                       // 512 KB
    float* sp      = (float*)(base + 524288);            // 64 KB
    float* sn      = (float*)(base + 524288 + 65536);    // 64 KB
    int*   cnt1    = (int*)(base + 524288 + 131072);     // 128 B
    int*   cnt0    = cnt1 + NB;                          // 128 B
    float* partial = (float*)(base + 524288 + 131072 + 256);  // 1 KB

    (void)hipMemsetAsync(cnt1, 0, 2 * NB * sizeof(int), stream);
    prep_w1t<<<HP, 256, 0, stream>>>(W1, w1t);
    encoder_mfma<<<NN / 16, 512, 0, stream>>>(q, x, w1t, b1, W2, b2,
                                              b, y, sp, sn, cnt1, cnt0);
    pairsum_kernel<<<NB * 8, 256, 0, stream>>>(sp, sn, cnt1, cnt0, partial);
    finalize_kernel<<<1, 256, 0, stream>>>(partial, cnt1, cnt0, out);
}